// Round 3
// baseline (285.602 us; speedup 1.0000x reference)
//
#include <hip/hip_runtime.h>

#define NCONDS 50
#define EMB 64
#define ROW_STRIDE 51
#define OUT_STRIDE ((1 + NCONDS) * EMB)   // 3264 floats per row
#define NITER 13
#define NSLICE 8
#define SLICE_ROWS 12501u                  // ceil(100002/8): slice = idx/12501 in [0,7]
#define BIN_CAP 131072                     // expected ~102400/slice, +95-sigma headroom
#define P1_ROWS 64                         // rows per phase-1 block

typedef float f4 __attribute__((ext_vector_type(4)));
typedef unsigned long long u64;

// 16-lane-row sum reduction on the VALU via DPP row_ror (no DS pipe).
template<int CTRL>
__device__ __forceinline__ float dpp_add(float x) {
    int y = __builtin_amdgcn_update_dpp(0, __builtin_bit_cast(int, x),
                                        CTRL, 0xf, 0xf, true);
    return x + __builtin_bit_cast(float, y);
}
__device__ __forceinline__ float reduce16(float x) {
    x = dpp_add<0x121>(x);   // ror 1
    x = dpp_add<0x122>(x);   // ror 2
    x = dpp_add<0x124>(x);   // ror 4
    x = dpp_add<0x128>(x);   // ror 8
    return x;
}

// ---------------- Phase 1: event-norm + raw-ev output + slice binning ----------
// One block = 64 batch rows (4 waves x 16). Bins entries (idx<<32 | b<<6 | c)
// by slice with LDS-aggregated counts -> only 8 global atomics per block.
__global__ __launch_bounds__(256) void p1_bin(
    const int*   __restrict__ inp,
    const float* __restrict__ table,
    float*       __restrict__ out,
    float*       __restrict__ enbuf,
    u64*         __restrict__ bins,
    unsigned*    __restrict__ gcnt,
    int batch)
{
    __shared__ int      stash[P1_ROWS][ROW_STRIDE];  // 13056 B
    __shared__ unsigned lcnt[NSLICE];
    __shared__ unsigned loff[NSLICE];

    const int wv   = threadIdx.x >> 6;
    const int lane = threadIdx.x & 63;
    const int grp  = lane >> 4;
    const int gl   = lane & 15;
    const int rbase = blockIdx.x * P1_ROWS;

    if (threadIdx.x < NSLICE) lcnt[threadIdx.x] = 0;
    __syncthreads();

    // Pass A: load indices, stash, per-slice ballot counts; event-norm work.
    for (int r = wv; r < P1_ROWS; r += 4) {
        const int R = rbase + r;
        if (R >= batch) break;
        int ci = 0;
        if (lane < ROW_STRIDE) {
            ci = inp[(size_t)R * ROW_STRIDE + lane];
            stash[r][lane] = ci;
        }
        // Event row: normalize once, store en to workspace, raw ev to output.
        const int e_idx = __shfl(ci, 0);
        const f4 ev = *(const f4*)(table + (size_t)e_idx * EMB + gl * 4);
        const float es = reduce16(ev.x*ev.x + ev.y*ev.y + ev.z*ev.z + ev.w*ev.w);
        const f4 en = ev * rsqrtf(es);
        if (grp == 0) {
            *(f4*)(enbuf + (size_t)R * EMB + gl * 4) = en;
            __builtin_nontemporal_store(ev, (f4*)(out + (size_t)R * OUT_STRIDE + gl * 4));
        }
        // Slice counting: 8 ballots, leader lanes do the LDS atomics.
        const bool valid = (lane >= 1) && (lane <= NCONDS);
        const int  sl    = (int)((unsigned)ci / SLICE_ROWS);
        #pragma unroll
        for (int s = 0; s < NSLICE; ++s) {
            const u64 m = __ballot(valid && (sl == s));
            if (lane == s && m) atomicAdd(&lcnt[s], (unsigned)__popcll(m));
        }
    }
    __syncthreads();

    if (threadIdx.x < NSLICE)
        loff[threadIdx.x] = atomicAdd(&gcnt[threadIdx.x], lcnt[threadIdx.x]);
    __syncthreads();

    // Pass B: re-walk stash, place entries at unique in-slice positions.
    for (int r = wv; r < P1_ROWS; r += 4) {
        const int R = rbase + r;
        if (R >= batch) break;
        if (lane >= 1 && lane <= NCONDS) {
            const int ci = stash[r][lane];
            const int sl = (int)((unsigned)ci / SLICE_ROWS);
            const unsigned pos = atomicAdd(&loff[sl], 1u);
            if (pos < BIN_CAP)
                bins[(size_t)sl * BIN_CAP + pos] =
                    ((u64)(unsigned)ci << 32) | (unsigned)((R << 6) | (lane - 1));
        }
    }
}

// ---------------- Phase 2: slice-local gather + filter ----------
// blockIdx&7 -> slice (round-robins XCDs so each L2 caches one ~3.2MB slice).
// Wave takes contiguous 32-entry tiles: 8 entry-loads then 16 gathers issued
// back-to-back (dense lanes, MLP >= baseline), all cond gathers in-slice.
__global__ __launch_bounds__(256) void p2_filter(
    const float*    __restrict__ table,
    const float*    __restrict__ enbuf,
    const u64*      __restrict__ bins,
    const unsigned* __restrict__ gcnt,
    float*          __restrict__ out)
{
    const int wv   = threadIdx.x >> 6;
    const int lane = threadIdx.x & 63;
    const int grp  = lane >> 4;
    const int gl   = lane & 15;
    const int s    = blockIdx.x & (NSLICE - 1);
    const int w    = (blockIdx.x >> 3) * 4 + wv;     // wave id within slice, 0..511

    unsigned count = gcnt[s];
    if (count > BIN_CAP) count = BIN_CAP;
    count = __builtin_amdgcn_readfirstlane(count);
    const unsigned per   = (count + 511) >> 9;        // 512 waves per slice
    const unsigned start = (unsigned)w * per;
    unsigned end = start + per;
    if (end > count) end = count;
    if (start >= end) return;

    const u64* bs = bins + (size_t)s * BIN_CAP;

    for (unsigned e0 = start; e0 < end; e0 += 32) {
        u64 ent[8];
        f4  v[8], en[8];
        #pragma unroll
        for (int r = 0; r < 8; ++r) {
            const unsigned e = e0 + r * 4 + grp;
            ent[r] = bs[e < end ? e : end - 1];
        }
        #pragma unroll
        for (int r = 0; r < 8; ++r) {
            const unsigned idx = (unsigned)(ent[r] >> 32);
            const unsigned b   = ((unsigned)ent[r] & 0xFFFFFu) >> 6;
            v[r]  = *(const f4*)(table + (size_t)idx * EMB + gl * 4);
            en[r] = *(const f4*)(enbuf + (size_t)b   * EMB + gl * 4);
        }
        #pragma unroll
        for (int r = 0; r < 8; ++r) {
            const unsigned bc = (unsigned)ent[r] & 0xFFFFFu;
            const unsigned b  = bc >> 6;
            const unsigned c  = bc & 63u;
            const f4 vv = v[r], ee = en[r];
            const float cs = reduce16(vv.x*vv.x + vv.y*vv.y + vv.z*vv.z + vv.w*vv.w);
            const float dp = reduce16(vv.x*ee.x + vv.y*ee.y + vv.z*ee.z + vv.w*ee.w);
            const float scale = dp * __builtin_amdgcn_rcpf(cs);
            const unsigned e = e0 + r * 4 + grp;
            if (e < end) {
                const f4 o = vv * scale;
                __builtin_nontemporal_store(o,
                    (f4*)(out + (size_t)b * OUT_STRIDE + EMB + (size_t)c * EMB + gl * 4));
            }
        }
    }
}

// ---------------- Fallback: round-0 baseline (used if ws too small) ----------
__global__ __launch_bounds__(256) void cond_filter_kernel(
    const int*   __restrict__ inp,
    const float* __restrict__ table,
    float*       __restrict__ out,
    int batch)
{
    const int wave = threadIdx.x >> 6;
    const int lane = threadIdx.x & 63;
    int b = blockIdx.x * 4 + wave;
    b = __builtin_amdgcn_readfirstlane(b);
    if (b >= batch) return;

    const int grp = lane >> 4;
    const int gl  = lane & 15;

    const int* row = inp + (size_t)b * ROW_STRIDE;
    const int e_idx = row[0];

    int cidx[NITER];
    #pragma unroll
    for (int i = 0; i < NITER; ++i) {
        const int base = 1 + i * 4;
        const int s0 = row[base];
        const int s1 = (base + 1 < ROW_STRIDE) ? row[base + 1] : s0;
        const int s2 = (base + 2 < ROW_STRIDE) ? row[base + 2] : s0;
        const int s3 = (base + 3 < ROW_STRIDE) ? row[base + 3] : s0;
        cidx[i] = (grp & 1) ? ((grp & 2) ? s3 : s1)
                            : ((grp & 2) ? s2 : s0);
    }

    const f4 ev = *(const f4*)(table + (size_t)e_idx * EMB + gl * 4);
    f4 cv[NITER];
    #pragma unroll
    for (int i = 0; i < NITER; ++i)
        cv[i] = *(const f4*)(table + (size_t)cidx[i] * EMB + gl * 4);

    const float es = reduce16(ev.x*ev.x + ev.y*ev.y + ev.z*ev.z + ev.w*ev.w);
    const f4 en = ev * rsqrtf(es);

    float* orow = out + (size_t)b * OUT_STRIDE;
    if (grp == 0)
        __builtin_nontemporal_store(ev, (f4*)(orow + gl * 4));

    #pragma unroll
    for (int i = 0; i < NITER; ++i) {
        const int c = i * 4 + grp;
        const f4 v = cv[i];
        const float cs = reduce16(v.x*v.x + v.y*v.y + v.z*v.z + v.w*v.w);
        const float dp = reduce16(v.x*en.x + v.y*en.y + v.z*en.z + v.w*en.w);
        const float scale = dp * __builtin_amdgcn_rcpf(cs);
        if (c < NCONDS) {
            const f4 o = v * scale;
            __builtin_nontemporal_store(o, (f4*)(orow + EMB + (size_t)c * EMB + gl * 4));
        }
    }
}

extern "C" void kernel_launch(void* const* d_in, const int* in_sizes, int n_in,
                              void* d_out, int out_size, void* d_ws, size_t ws_size,
                              hipStream_t stream) {
    const int*   inp   = (const int*)d_in[0];
    const float* table = (const float*)d_in[1];
    float*       out   = (float*)d_out;

    const int batch = in_sizes[0] / ROW_STRIDE;   // 16384

    const size_t bins_bytes = (size_t)NSLICE * BIN_CAP * sizeof(u64);  // 8 MiB
    const size_t en_bytes   = (size_t)batch * EMB * sizeof(float);     // 4 MiB
    const size_t need       = 256 + bins_bytes + en_bytes;

    if (d_ws != nullptr && ws_size >= need) {
        unsigned* gcnt  = (unsigned*)d_ws;
        u64*      bins  = (u64*)((char*)d_ws + 256);
        float*    enbuf = (float*)((char*)d_ws + 256 + bins_bytes);

        hipMemsetAsync(gcnt, 0, 64, stream);

        const int blocks1 = (batch + P1_ROWS - 1) / P1_ROWS;   // 256
        hipLaunchKernelGGL(p1_bin, dim3(blocks1), dim3(256), 0, stream,
                           inp, table, out, enbuf, bins, gcnt, batch);
        hipLaunchKernelGGL(p2_filter, dim3(1024), dim3(256), 0, stream,
                           table, enbuf, bins, gcnt, out);
    } else {
        const int blocks = (batch + 3) / 4;
        hipLaunchKernelGGL(cond_filter_kernel, dim3(blocks), dim3(256), 0, stream,
                           inp, table, out, batch);
    }
}